// Round 2
// baseline (1082.753 us; speedup 1.0000x reference)
//
#include <hip/hip_runtime.h>

typedef __bf16 bf16;
typedef __attribute__((ext_vector_type(8))) __bf16 bf16x8;
typedef __attribute__((ext_vector_type(4))) float f32x4;
typedef __attribute__((ext_vector_type(4))) int int4v;

typedef __attribute__((address_space(1))) const void gconst_t;
typedef __attribute__((address_space(3))) void lvoid_t;

#define SEQ 4096
#define D_IN 2048
#define NHEADS 16
#define MLA_SCALE 0.08838834764831843f
#define RMS_EPS 1e-6f

// ---------------------------------------------------------------- conversions
__global__ __launch_bounds__(256) void f32_to_bf16_kernel(
    const float* __restrict__ in, bf16* __restrict__ out, int n) {
    int i = (blockIdx.x * 256 + threadIdx.x) * 4;
    int stride = gridDim.x * 256 * 4;
    for (; i < n; i += stride) {
        float4 v = *reinterpret_cast<const float4*>(in + i);
        bf16 o[4];
        o[0] = (bf16)v.x; o[1] = (bf16)v.y; o[2] = (bf16)v.z; o[3] = (bf16)v.w;
        *reinterpret_cast<uint2*>(out + i) = *reinterpret_cast<uint2*>(o);
    }
}

// ---------------------------------------------------------------- generic GEMM (m97 structure)
// C[M,N] = A[M,K](bf16,row-major) * B[N,K](bf16,row-major)^T
// 128x128 tile, BK=32, 4 waves (2x2 of 64x64), linear LDS + global_load_lds(16B).
template<bool BF16_OUT>
__global__ __launch_bounds__(256) void gemm_bt_kernel(
    const bf16* __restrict__ A, const bf16* __restrict__ B, void* __restrict__ Cout,
    int M, int N, int K) {
    __shared__ __align__(16) bf16 Al[128 * 32];
    __shared__ __align__(16) bf16 Bl[128 * 32];
    int tid  = threadIdx.x;
    int lane = tid & 63;
    int w    = tid >> 6;
    int wr = w >> 1, wc = w & 1;
    int m0 = blockIdx.y * 128;
    int n0 = blockIdx.x * 128;
    int l15 = lane & 15;
    int g   = lane >> 4;

    // staging geometry: call c (0,1), wave w, lane l covers LDS elems
    //   base = c*2048 + w*512 (+ l*8 implicit)  -> row = c*64 + w*16 + (l>>2), col = (l&3)*8
    int srow = (lane >> 2);
    int scol = (lane & 3) * 8;

    f32x4 acc[4][4] = {};

    for (int k0 = 0; k0 < K; k0 += 32) {
        __syncthreads();  // previous iteration's LDS reads done
        #pragma unroll
        for (int c = 0; c < 2; c++) {
            int arow = m0 + c*64 + w*16 + srow;
            const bf16* ga = A + (size_t)arow * K + k0 + scol;
            __builtin_amdgcn_global_load_lds((gconst_t*)ga, (lvoid_t*)&Al[c*2048 + w*512], 16, 0, 0);
            int brow = n0 + c*64 + w*16 + srow; if (brow >= N) brow = N - 1;
            const bf16* gb = B + (size_t)brow * K + k0 + scol;
            __builtin_amdgcn_global_load_lds((gconst_t*)gb, (lvoid_t*)&Bl[c*2048 + w*512], 16, 0, 0);
        }
        __syncthreads();  // drains vmcnt -> LDS valid
        bf16x8 af[4], bfv[4];
        #pragma unroll
        for (int mt = 0; mt < 4; mt++)
            af[mt] = *reinterpret_cast<const bf16x8*>(&Al[(wr*64 + mt*16 + l15) * 32 + g*8]);
        #pragma unroll
        for (int nt = 0; nt < 4; nt++)
            bfv[nt] = *reinterpret_cast<const bf16x8*>(&Bl[(wc*64 + nt*16 + l15) * 32 + g*8]);
        #pragma unroll
        for (int mt = 0; mt < 4; mt++)
            #pragma unroll
            for (int nt = 0; nt < 4; nt++)
                acc[mt][nt] = __builtin_amdgcn_mfma_f32_16x16x32_bf16(af[mt], bfv[nt], acc[mt][nt], 0, 0, 0);
    }

    #pragma unroll
    for (int mt = 0; mt < 4; mt++) {
        #pragma unroll
        for (int nt = 0; nt < 4; nt++) {
            int col = n0 + wc*64 + nt*16 + l15;
            if (col < N) {
                #pragma unroll
                for (int r = 0; r < 4; r++) {
                    int row = m0 + wr*64 + mt*16 + g*4 + r;
                    if (BF16_OUT)
                        ((bf16*)Cout)[(size_t)row * N + col] = (bf16)acc[mt][nt][r];
                    else
                        ((float*)Cout)[(size_t)row * N + col] = acc[mt][nt][r];
                }
            }
        }
    }
}

// ---------------------------------------------------------------- q prep (rope + scale, in place)
__global__ __launch_bounds__(256) void prep_q_kernel(
    bf16* __restrict__ q, const float* __restrict__ cosb, const float* __restrict__ sinb) {
    int s = blockIdx.x;
    int t = threadIdx.x;
    bf16* p = q + (size_t)s * 2048 + t * 8;
    bf16x8 v = *reinterpret_cast<bf16x8*>(p);
    float f[8];
    #pragma unroll
    for (int j = 0; j < 8; j++) f[j] = (float)v[j];
    int d0 = (t & 15) * 8;
    if (d0 >= 64) {
        int ib = (d0 - 64) >> 1;
        #pragma unroll
        for (int pr = 0; pr < 4; pr++) {
            float c  = cosb[s * 32 + ib + pr];
            float sn = sinb[s * 32 + ib + pr];
            float xe = f[pr*2], xo = f[pr*2 + 1];
            f[pr*2]     = xe * c - xo * sn;
            f[pr*2 + 1] = xe * sn + xo * c;
        }
    }
    #pragma unroll
    for (int j = 0; j < 8; j++) v[j] = (bf16)(f[j] * MLA_SCALE);
    *reinterpret_cast<bf16x8*>(p) = v;
}

// ---------------------------------------------------------------- kv prep (rmsnorm + k_pe rope)
__global__ __launch_bounds__(256) void prep_kv_kernel(
    const bf16* __restrict__ kvfull, const float* __restrict__ w,
    const float* __restrict__ cosb, const float* __restrict__ sinb,
    bf16* __restrict__ kvnorm, bf16* __restrict__ kpe) {
    __shared__ float red[4];
    int s = blockIdx.x;
    int t = threadIdx.x;
    const bf16* src = kvfull + (size_t)s * 1088;
    float f[4];
    {
        uint2 raw = *reinterpret_cast<const uint2*>(src + t * 4);
        bf16* vb = reinterpret_cast<bf16*>(&raw);
        float ss = 0.f;
        #pragma unroll
        for (int j = 0; j < 4; j++) { f[j] = (float)vb[j]; ss += f[j] * f[j]; }
        #pragma unroll
        for (int m = 1; m < 64; m <<= 1) ss += __shfl_xor(ss, m);
        if ((t & 63) == 0) red[t >> 6] = ss;
    }
    __syncthreads();
    float tot = red[0] + red[1] + red[2] + red[3];
    float rms = rsqrtf(tot * (1.0f / 1024.0f) + RMS_EPS);
    bf16 o[4];
    #pragma unroll
    for (int j = 0; j < 4; j++) o[j] = (bf16)(f[j] * rms * w[t*4 + j]);
    *reinterpret_cast<uint2*>(kvnorm + (size_t)s * 1024 + t * 4) = *reinterpret_cast<uint2*>(o);
    if (t < 16) {
        float e[4];
        #pragma unroll
        for (int j = 0; j < 4; j++) e[j] = (float)src[1024 + t*4 + j];
        int ib = t * 2;
        float c0 = cosb[s*32 + ib],     s0 = sinb[s*32 + ib];
        float c1 = cosb[s*32 + ib + 1], s1 = sinb[s*32 + ib + 1];
        bf16 ko[4];
        ko[0] = (bf16)(e[0]*c0 - e[1]*s0);
        ko[1] = (bf16)(e[0]*s0 + e[1]*c0);
        ko[2] = (bf16)(e[2]*c1 - e[3]*s1);
        ko[3] = (bf16)(e[2]*s1 + e[3]*c1);
        *reinterpret_cast<uint2*>(kpe + (size_t)s * 64 + t * 4) = *reinterpret_cast<uint2*>(ko);
    }
}

// ---------------------------------------------------------------- build Vt[h][128][4096]
__global__ __launch_bounds__(256) void build_vt_kernel(
    const bf16* __restrict__ kvb, bf16* __restrict__ vt) {
    const int LT = 130; // odd-dword stride -> conflict-free column reads
    __shared__ bf16 lt[64 * 130];
    int h  = blockIdx.y;
    int s0 = blockIdx.x * 64;
    int t  = threadIdx.x;
    {
        int row = t >> 2;            // 0..63
        int d0  = (t & 3) * 32;      // 32 bf16 = 64B per thread
        const bf16* src = kvb + (size_t)(s0 + row) * 3072 + h * 192 + 64 + d0;
        int4v v0 = *reinterpret_cast<const int4v*>(src);
        int4v v1 = *reinterpret_cast<const int4v*>(src + 8);
        int4v v2 = *reinterpret_cast<const int4v*>(src + 16);
        int4v v3 = *reinterpret_cast<const int4v*>(src + 24);
        int* dst = reinterpret_cast<int*>(&lt[row * LT + d0]); // 4B aligned
        int* s0p = reinterpret_cast<int*>(&v0); int* s1p = reinterpret_cast<int*>(&v1);
        int* s2p = reinterpret_cast<int*>(&v2); int* s3p = reinterpret_cast<int*>(&v3);
        #pragma unroll
        for (int j = 0; j < 4; j++) { dst[j] = s0p[j]; dst[4+j] = s1p[j]; dst[8+j] = s2p[j]; dst[12+j] = s3p[j]; }
    }
    __syncthreads();
    int ss = t & 63;
    int db = t >> 6;
    bf16* out = vt + (size_t)h * 128 * 4096 + s0 + ss;
    #pragma unroll
    for (int dd = db; dd < 128; dd += 4)
        out[(size_t)dd * 4096] = lt[ss * LT + dd];
}

// ---------------------------------------------------------------- flash attention v2
// No __syncthreads in main loop. K/V fragments loaded directly from global
// (L1/L2-resident). 4 waves x 16 q-rows, KVBLK=64, heavy-first ordering.
__global__ __launch_bounds__(256) void attn_kernel(
    const bf16* __restrict__ q,     // [4096][2048]  (roped, *SCALE)
    const bf16* __restrict__ kvb,   // [4096][3072]
    const bf16* __restrict__ kpe,   // [4096][64]
    const bf16* __restrict__ vt,    // [16][128][4096]
    bf16* __restrict__ attn) {      // [4096][2048]
    const int LPS = 72; // P row stride (bf16): 144B = 9*16B, 2-way-free on b128 reads
    __shared__ __align__(16) bf16 Pl[4][16 * 72];

    int h  = blockIdx.y;
    int q0 = ((int)gridDim.x - 1 - (int)blockIdx.x) * 64;  // heavy tiles first
    int t  = threadIdx.x;
    int lane = t & 63;
    int w  = t >> 6;
    int l15 = lane & 15;
    int g   = lane >> 4;
    int qrow = q0 + w * 16;
    int imax = qrow + 15;

    bf16x8 qf[4];
    {
        const bf16* qp = q + (size_t)(qrow + l15) * 2048 + h * 128 + g * 8;
        #pragma unroll
        for (int c = 0; c < 4; c++) qf[c] = *reinterpret_cast<const bf16x8*>(qp + c * 32);
    }

    const bf16* kvbh = kvb + h * 192;
    const bf16* vth  = vt + (size_t)h * 524288;

    f32x4 o[8] = {};
    float mrow[4], lrow[4];
    #pragma unroll
    for (int r = 0; r < 4; r++) { mrow[r] = -3e38f; lrow[r] = 0.f; }

    int nch = (q0 >> 6) + 1;
    for (int jc = 0; jc < nch; ++jc) {
        int j0 = jc << 6;
        f32x4 sfr[4];
        #pragma unroll
        for (int sub = 0; sub < 4; ++sub) {
            int jbase = j0 + sub * 16;
            if (jbase <= imax) {                 // wave-uniform branch
                int jrow = jbase + l15;
                const bf16* kn = kvbh + (size_t)jrow * 3072 + g * 8;
                const bf16* kp = kpe + (size_t)jrow * 64 + g * 8;
                f32x4 s = {};
                s = __builtin_amdgcn_mfma_f32_16x16x32_bf16(qf[0], *reinterpret_cast<const bf16x8*>(kn),      s, 0, 0, 0);
                s = __builtin_amdgcn_mfma_f32_16x16x32_bf16(qf[1], *reinterpret_cast<const bf16x8*>(kn + 32), s, 0, 0, 0);
                s = __builtin_amdgcn_mfma_f32_16x16x32_bf16(qf[2], *reinterpret_cast<const bf16x8*>(kp),      s, 0, 0, 0);
                s = __builtin_amdgcn_mfma_f32_16x16x32_bf16(qf[3], *reinterpret_cast<const bf16x8*>(kp + 32), s, 0, 0, 0);
                sfr[sub] = s;
            } else {
                f32x4 neg = {-3e38f, -3e38f, -3e38f, -3e38f};
                sfr[sub] = neg;
            }
        }
        float sfac[4];
        #pragma unroll
        for (int r = 0; r < 4; ++r) {
            int i = qrow + g * 4 + r;
            #pragma unroll
            for (int sub = 0; sub < 4; ++sub) {
                int j = j0 + sub * 16 + l15;
                if (j > i) sfr[sub][r] = -3e38f;
            }
            float mx = fmaxf(fmaxf(sfr[0][r], sfr[1][r]), fmaxf(sfr[2][r], sfr[3][r]));
            #pragma unroll
            for (int m = 1; m < 16; m <<= 1) mx = fmaxf(mx, __shfl_xor(mx, m));
            float mnew = fmaxf(mrow[r], mx);
            sfac[r] = __expf(mrow[r] - mnew);
            mrow[r] = mnew;
            float p0 = __expf(sfr[0][r] - mnew);
            float p1 = __expf(sfr[1][r] - mnew);
            float p2 = __expf(sfr[2][r] - mnew);
            float p3 = __expf(sfr[3][r] - mnew);
            sfr[0][r] = p0; sfr[1][r] = p1; sfr[2][r] = p2; sfr[3][r] = p3;
            float ps = (p0 + p1) + (p2 + p3);
            #pragma unroll
            for (int m = 1; m < 16; m <<= 1) ps += __shfl_xor(ps, m);
            lrow[r] = lrow[r] * sfac[r] + ps;
        }
        #pragma unroll
        for (int dt = 0; dt < 8; dt++)
            #pragma unroll
            for (int r = 0; r < 4; r++) o[dt][r] *= sfac[r];
        #pragma unroll
        for (int sub = 0; sub < 4; ++sub)
            #pragma unroll
            for (int r = 0; r < 4; r++)
                Pl[w][(g*4 + r) * LPS + sub*16 + l15] = (bf16)sfr[sub][r];
        // same-wave LDS round-trip; compiler inserts lgkmcnt wait
        bf16x8 pf0 = *reinterpret_cast<const bf16x8*>(&Pl[w][l15 * LPS + g * 8]);
        bf16x8 pf1 = *reinterpret_cast<const bf16x8*>(&Pl[w][l15 * LPS + 32 + g * 8]);
        bool do2 = (j0 + 32) <= imax;            // wave-uniform
        #pragma unroll
        for (int dt = 0; dt < 8; dt++) {
            const bf16* vp = vth + (size_t)(dt*16 + l15) * 4096 + j0 + g * 8;
            o[dt] = __builtin_amdgcn_mfma_f32_16x16x32_bf16(pf0, *reinterpret_cast<const bf16x8*>(vp), o[dt], 0, 0, 0);
            if (do2)
                o[dt] = __builtin_amdgcn_mfma_f32_16x16x32_bf16(pf1, *reinterpret_cast<const bf16x8*>(vp + 32), o[dt], 0, 0, 0);
        }
    }
    #pragma unroll
    for (int r = 0; r < 4; r++) {
        float inv = 1.0f / lrow[r];
        int i = qrow + g * 4 + r;
        #pragma unroll
        for (int dt = 0; dt < 8; dt++)
            attn[(size_t)i * 2048 + h * 128 + dt*16 + l15] = (bf16)(o[dt][r] * inv);
    }
}

// ---------------------------------------------------------------- launch
extern "C" void kernel_launch(void* const* d_in, const int* in_sizes, int n_in,
                              void* d_out, int out_size, void* d_ws, size_t ws_size,
                              hipStream_t stream) {
    const float* x    = (const float*)d_in[0];
    const float* cosb = (const float*)d_in[1];
    const float* sinb = (const float*)d_in[2];
    // d_in[3] = mask (unused: causal, start_pos=0)
    const float* wq   = (const float*)d_in[4];
    const float* wkva = (const float*)d_in[5];
    const float* kvw  = (const float*)d_in[6];
    const float* wkvb = (const float*)d_in[7];
    const float* wo   = (const float*)d_in[8];
    // d_in[9] = start_pos (0)

    char* ws = (char*)d_ws;
    bf16* x_bf    = (bf16*)(ws + 0);          // 16.7MB; later reused as kvnorm, then attn
    bf16* kvnorm  = (bf16*)(ws + 0);
    bf16* attn    = (bf16*)(ws + 0);
    bf16* wq_bf   = (bf16*)(ws + 16777216);
    bf16* wkva_bf = (bf16*)(ws + 25165824);
    bf16* wkvb_bf = (bf16*)(ws + 29622272);
    bf16* wo_bf   = (bf16*)(ws + 35913728);
    bf16* q_bf    = (bf16*)(ws + 44302336);
    bf16* kvfull  = (bf16*)(ws + 61079552);
    bf16* kpe     = (bf16*)(ws + 69992448);
    bf16* kvb     = (bf16*)(ws + 70516736);
    bf16* vt      = (bf16*)(ws + 95682560);
    // total: 112459776 bytes

    f32_to_bf16_kernel<<<dim3(512), dim3(256), 0, stream>>>(x,    x_bf,    4096*2048);
    f32_to_bf16_kernel<<<dim3(512), dim3(256), 0, stream>>>(wq,   wq_bf,   2048*2048);
    f32_to_bf16_kernel<<<dim3(512), dim3(256), 0, stream>>>(wkva, wkva_bf, 1088*2048);
    f32_to_bf16_kernel<<<dim3(512), dim3(256), 0, stream>>>(wkvb, wkvb_bf, 3072*1024);
    f32_to_bf16_kernel<<<dim3(512), dim3(256), 0, stream>>>(wo,   wo_bf,   2048*2048);

    gemm_bt_kernel<true><<<dim3(16, 32), dim3(256), 0, stream>>>(x_bf, wq_bf,   q_bf,   4096, 2048, 2048);
    gemm_bt_kernel<true><<<dim3(9,  32), dim3(256), 0, stream>>>(x_bf, wkva_bf, kvfull, 4096, 1088, 2048);

    prep_q_kernel <<<dim3(4096), dim3(256), 0, stream>>>(q_bf, cosb, sinb);
    prep_kv_kernel<<<dim3(4096), dim3(256), 0, stream>>>(kvfull, kvw, cosb, sinb, kvnorm, kpe);

    gemm_bt_kernel<true><<<dim3(24, 32), dim3(256), 0, stream>>>(kvnorm, wkvb_bf, kvb, 4096, 3072, 1024);

    build_vt_kernel<<<dim3(64, 16), dim3(256), 0, stream>>>(kvb, vt);

    attn_kernel<<<dim3(64, 16), dim3(256), 0, stream>>>(q_bf, kvb, kpe, vt, attn);

    gemm_bt_kernel<false><<<dim3(16, 32), dim3(256), 0, stream>>>(attn, wo_bf, (float*)d_out, 4096, 2048, 2048);
}

// Round 3
// 535.235 us; speedup vs baseline: 2.0229x; 2.0229x over previous
//
#include <hip/hip_runtime.h>

typedef __bf16 bf16;
typedef __attribute__((ext_vector_type(8))) __bf16 bf16x8;
typedef __attribute__((ext_vector_type(4))) float f32x4;
typedef __attribute__((ext_vector_type(4))) int int4v;

typedef __attribute__((address_space(1))) const void gconst_t;
typedef __attribute__((address_space(3))) void lvoid_t;

#define SEQ 4096
#define D_IN 2048
#define NHEADS 16
// SCALE * log2(e): attention computed in exp2 domain
#define QSCALE (0.08838834764831843f * 1.4426950408889634f)
#define RMS_EPS 1e-6f

// ---------------------------------------------------------------- conversions
__global__ __launch_bounds__(256) void f32_to_bf16_kernel(
    const float* __restrict__ in, bf16* __restrict__ out, int n) {
    int i = (blockIdx.x * 256 + threadIdx.x) * 4;
    int stride = gridDim.x * 256 * 4;
    for (; i < n; i += stride) {
        float4 v = *reinterpret_cast<const float4*>(in + i);
        bf16 o[4];
        o[0] = (bf16)v.x; o[1] = (bf16)v.y; o[2] = (bf16)v.z; o[3] = (bf16)v.w;
        *reinterpret_cast<uint2*>(out + i) = *reinterpret_cast<uint2*>(o);
    }
}

// ---------------------------------------------------------------- generic GEMM (m97 structure)
template<bool BF16_OUT>
__global__ __launch_bounds__(256) void gemm_bt_kernel(
    const bf16* __restrict__ A, const bf16* __restrict__ B, void* __restrict__ Cout,
    int M, int N, int K) {
    __shared__ __align__(16) bf16 Al[128 * 32];
    __shared__ __align__(16) bf16 Bl[128 * 32];
    int tid  = threadIdx.x;
    int lane = tid & 63;
    int w    = tid >> 6;
    int wr = w >> 1, wc = w & 1;
    int m0 = blockIdx.y * 128;
    int n0 = blockIdx.x * 128;
    int l15 = lane & 15;
    int g   = lane >> 4;

    int srow = (lane >> 2);
    int scol = (lane & 3) * 8;

    f32x4 acc[4][4] = {};

    for (int k0 = 0; k0 < K; k0 += 32) {
        __syncthreads();
        #pragma unroll
        for (int c = 0; c < 2; c++) {
            int arow = m0 + c*64 + w*16 + srow;
            const bf16* ga = A + (size_t)arow * K + k0 + scol;
            __builtin_amdgcn_global_load_lds((gconst_t*)ga, (lvoid_t*)&Al[c*2048 + w*512], 16, 0, 0);
            int brow = n0 + c*64 + w*16 + srow; if (brow >= N) brow = N - 1;
            const bf16* gb = B + (size_t)brow * K + k0 + scol;
            __builtin_amdgcn_global_load_lds((gconst_t*)gb, (lvoid_t*)&Bl[c*2048 + w*512], 16, 0, 0);
        }
        __syncthreads();
        bf16x8 af[4], bfv[4];
        #pragma unroll
        for (int mt = 0; mt < 4; mt++)
            af[mt] = *reinterpret_cast<const bf16x8*>(&Al[(wr*64 + mt*16 + l15) * 32 + g*8]);
        #pragma unroll
        for (int nt = 0; nt < 4; nt++)
            bfv[nt] = *reinterpret_cast<const bf16x8*>(&Bl[(wc*64 + nt*16 + l15) * 32 + g*8]);
        #pragma unroll
        for (int mt = 0; mt < 4; mt++)
            #pragma unroll
            for (int nt = 0; nt < 4; nt++)
                acc[mt][nt] = __builtin_amdgcn_mfma_f32_16x16x32_bf16(af[mt], bfv[nt], acc[mt][nt], 0, 0, 0);
    }

    #pragma unroll
    for (int mt = 0; mt < 4; mt++) {
        #pragma unroll
        for (int nt = 0; nt < 4; nt++) {
            int col = n0 + wc*64 + nt*16 + l15;
            if (col < N) {
                #pragma unroll
                for (int r = 0; r < 4; r++) {
                    int row = m0 + wr*64 + mt*16 + g*4 + r;
                    if (BF16_OUT)
                        ((bf16*)Cout)[(size_t)row * N + col] = (bf16)acc[mt][nt][r];
                    else
                        ((float*)Cout)[(size_t)row * N + col] = acc[mt][nt][r];
                }
            }
        }
    }
}

// ---------------------------------------------------------------- q prep (rope + scale*log2e, in place)
__global__ __launch_bounds__(256) void prep_q_kernel(
    bf16* __restrict__ q, const float* __restrict__ cosb, const float* __restrict__ sinb) {
    int s = blockIdx.x;
    int t = threadIdx.x;
    bf16* p = q + (size_t)s * 2048 + t * 8;
    bf16x8 v = *reinterpret_cast<bf16x8*>(p);
    float f[8];
    #pragma unroll
    for (int j = 0; j < 8; j++) f[j] = (float)v[j];
    int d0 = (t & 15) * 8;
    if (d0 >= 64) {
        int ib = (d0 - 64) >> 1;
        #pragma unroll
        for (int pr = 0; pr < 4; pr++) {
            float c  = cosb[s * 32 + ib + pr];
            float sn = sinb[s * 32 + ib + pr];
            float xe = f[pr*2], xo = f[pr*2 + 1];
            f[pr*2]     = xe * c - xo * sn;
            f[pr*2 + 1] = xe * sn + xo * c;
        }
    }
    #pragma unroll
    for (int j = 0; j < 8; j++) v[j] = (bf16)(f[j] * QSCALE);
    *reinterpret_cast<bf16x8*>(p) = v;
}

// ---------------------------------------------------------------- kv prep (rmsnorm + k_pe rope)
__global__ __launch_bounds__(256) void prep_kv_kernel(
    const bf16* __restrict__ kvfull, const float* __restrict__ w,
    const float* __restrict__ cosb, const float* __restrict__ sinb,
    bf16* __restrict__ kvnorm, bf16* __restrict__ kpe) {
    __shared__ float red[4];
    int s = blockIdx.x;
    int t = threadIdx.x;
    const bf16* src = kvfull + (size_t)s * 1088;
    float f[4];
    {
        uint2 raw = *reinterpret_cast<const uint2*>(src + t * 4);
        bf16* vb = reinterpret_cast<bf16*>(&raw);
        float ss = 0.f;
        #pragma unroll
        for (int j = 0; j < 4; j++) { f[j] = (float)vb[j]; ss += f[j] * f[j]; }
        #pragma unroll
        for (int m = 1; m < 64; m <<= 1) ss += __shfl_xor(ss, m);
        if ((t & 63) == 0) red[t >> 6] = ss;
    }
    __syncthreads();
    float tot = red[0] + red[1] + red[2] + red[3];
    float rms = rsqrtf(tot * (1.0f / 1024.0f) + RMS_EPS);
    bf16 o[4];
    #pragma unroll
    for (int j = 0; j < 4; j++) o[j] = (bf16)(f[j] * rms * w[t*4 + j]);
    *reinterpret_cast<uint2*>(kvnorm + (size_t)s * 1024 + t * 4) = *reinterpret_cast<uint2*>(o);
    if (t < 16) {
        float e[4];
        #pragma unroll
        for (int j = 0; j < 4; j++) e[j] = (float)src[1024 + t*4 + j];
        int ib = t * 2;
        float c0 = cosb[s*32 + ib],     s0 = sinb[s*32 + ib];
        float c1 = cosb[s*32 + ib + 1], s1 = sinb[s*32 + ib + 1];
        bf16 ko[4];
        ko[0] = (bf16)(e[0]*c0 - e[1]*s0);
        ko[1] = (bf16)(e[0]*s0 + e[1]*c0);
        ko[2] = (bf16)(e[2]*c1 - e[3]*s1);
        ko[3] = (bf16)(e[2]*s1 + e[3]*c1);
        *reinterpret_cast<uint2*>(kpe + (size_t)s * 64 + t * 4) = *reinterpret_cast<uint2*>(ko);
    }
}

// ---------------------------------------------------------------- build Vt[h][128][4096]
__global__ __launch_bounds__(256) void build_vt_kernel(
    const bf16* __restrict__ kvb, bf16* __restrict__ vt) {
    const int LT = 130;
    __shared__ bf16 lt[64 * 130];
    int h  = blockIdx.y;
    int s0 = blockIdx.x * 64;
    int t  = threadIdx.x;
    {
        int row = t >> 2;
        int d0  = (t & 3) * 32;
        const bf16* src = kvb + (size_t)(s0 + row) * 3072 + h * 192 + 64 + d0;
        int4v v0 = *reinterpret_cast<const int4v*>(src);
        int4v v1 = *reinterpret_cast<const int4v*>(src + 8);
        int4v v2 = *reinterpret_cast<const int4v*>(src + 16);
        int4v v3 = *reinterpret_cast<const int4v*>(src + 24);
        int* dst = reinterpret_cast<int*>(&lt[row * LT + d0]);
        int* s0p = reinterpret_cast<int*>(&v0); int* s1p = reinterpret_cast<int*>(&v1);
        int* s2p = reinterpret_cast<int*>(&v2); int* s3p = reinterpret_cast<int*>(&v3);
        #pragma unroll
        for (int j = 0; j < 4; j++) { dst[j] = s0p[j]; dst[4+j] = s1p[j]; dst[8+j] = s2p[j]; dst[12+j] = s3p[j]; }
    }
    __syncthreads();
    int ss = t & 63;
    int db = t >> 6;
    bf16* out = vt + (size_t)h * 128 * 4096 + s0 + ss;
    #pragma unroll
    for (int dd = db; dd < 128; dd += 4)
        out[(size_t)dd * 4096] = lt[ss * LT + dd];
}

// ---------------------------------------------------------------- flash attention v3
// QBLK=128 (4 waves x 32 rows, 2 m-tiles each), KVBLK=64, double-buffered
// K/V LDS via global_load_lds with XOR-swizzled source (T2 via m173 pattern),
// one barrier per chunk (2-phase prefetch), exp2-domain softmax.
__global__ __launch_bounds__(256, 2) void attn_kernel(
    const bf16* __restrict__ q,     // [4096][2048]  (roped, *QSCALE)
    const bf16* __restrict__ kvb,   // [4096][3072]
    const bf16* __restrict__ kpe,   // [4096][64]
    const bf16* __restrict__ vt,    // [16][128][4096]
    bf16* __restrict__ attn) {      // [4096][2048]
    const int LPS = 72;
    __shared__ __align__(16) bf16 Kl[2][64 * 128];   // 32 KB
    __shared__ __align__(16) bf16 Vl[2][128 * 64];   // 32 KB
    __shared__ __align__(16) bf16 Pl[4][16 * 72];    // 9 KB

    int h  = blockIdx.y;
    int q0 = ((int)gridDim.x - 1 - (int)blockIdx.x) * 128;  // heavy tiles first
    int t  = threadIdx.x;
    int lane = t & 63;
    int w  = t >> 6;
    int l15 = lane & 15;
    int g   = lane >> 4;
    int sw  = l15 & 7;              // read-side XOR swizzle key
    int qrow = q0 + w * 32;

    const bf16* kvbh = kvb + h * 192;
    const bf16* vth  = vt + (size_t)h * 524288;

    bf16x8 qf[2][4];
    #pragma unroll
    for (int mt = 0; mt < 2; mt++) {
        const bf16* qp = q + (size_t)(qrow + mt*16 + l15) * 2048 + h * 128 + g * 8;
        #pragma unroll
        for (int c = 0; c < 4; c++) qf[mt][c] = *reinterpret_cast<const bf16x8*>(qp + c * 32);
    }

    f32x4 o[2][8] = {};
    float mrow[2][4], lrow[2][4];
    #pragma unroll
    for (int mt = 0; mt < 2; mt++)
        #pragma unroll
        for (int r = 0; r < 4; r++) { mrow[mt][r] = -3e38f; lrow[mt][r] = 0.f; }

    int nch = (q0 >> 6) + 2;
    int dc  = (q0 >> 6) + (w >> 1);   // this wave's (only) masked chunk

    // --- staging: linear LDS dest (wave-uniform base + lane*16), XOR-swizzled
    //     global source so that ds_read with the same XOR is bank-uniform.
    auto stageK = [&](int jc, int buf) {
        int j0 = jc << 6;
        #pragma unroll
        for (int c = 0; c < 4; c++) {
            int idx = c*256 + w*64 + lane;   // 16B unit index in [0,1024)
            int row = idx >> 4;              // j within chunk
            int u   = (idx & 15) ^ (row & 7);
            const bf16* src = (u < 8)
                ? kvbh + (size_t)(j0 + row) * 3072 + u * 8
                : kpe  + (size_t)(j0 + row) * 64  + (u - 8) * 8;
            __builtin_amdgcn_global_load_lds((gconst_t*)src,
                (lvoid_t*)&Kl[buf][(c*256 + w*64) * 8], 16, 0, 0);
        }
    };
    auto stageV = [&](int jc, int buf) {
        int j0 = jc << 6;
        #pragma unroll
        for (int c = 0; c < 4; c++) {
            int idx = c*256 + w*64 + lane;   // 16B unit index in [0,1024)
            int row = idx >> 3;              // d in [0,128)
            int u   = (idx & 7) ^ (row & 7);
            const bf16* src = vth + (size_t)row * 4096 + j0 + u * 8;
            __builtin_amdgcn_global_load_lds((gconst_t*)src,
                (lvoid_t*)&Vl[buf][(c*256 + w*64) * 8], 16, 0, 0);
        }
    };

    stageK(0, 0); stageV(0, 0);

    for (int jc = 0; jc < nch; ++jc) {
        __syncthreads();                 // implicit vmcnt(0): chunk jc staged, prev reads done
        if (jc + 1 < nch) { stageK(jc + 1, (jc + 1) & 1); stageV(jc + 1, (jc + 1) & 1); }

        if (jc <= dc) {
            int cur = jc & 1;
            int j0  = jc << 6;
            bool masked = (jc == dc);

            // ---- QK^T: S[32q][64j] per wave
            f32x4 sfr[2][4];
            #pragma unroll
            for (int sub = 0; sub < 4; ++sub) {
                int krow = sub*16 + l15;
                bf16x8 kf[4];
                #pragma unroll
                for (int c = 0; c < 4; ++c)
                    kf[c] = *reinterpret_cast<const bf16x8*>(
                        &Kl[cur][krow*128 + (((c*4 + g) ^ sw) * 8)]);
                #pragma unroll
                for (int mt = 0; mt < 2; ++mt) {
                    f32x4 s = {};
                    s = __builtin_amdgcn_mfma_f32_16x16x32_bf16(qf[mt][0], kf[0], s, 0, 0, 0);
                    s = __builtin_amdgcn_mfma_f32_16x16x32_bf16(qf[mt][1], kf[1], s, 0, 0, 0);
                    s = __builtin_amdgcn_mfma_f32_16x16x32_bf16(qf[mt][2], kf[2], s, 0, 0, 0);
                    s = __builtin_amdgcn_mfma_f32_16x16x32_bf16(qf[mt][3], kf[3], s, 0, 0, 0);
                    sfr[mt][sub] = s;
                }
            }

            // ---- softmax + P staging per m-tile
            bf16x8 pf[2][2];
            #pragma unroll
            for (int mt = 0; mt < 2; ++mt) {
                int rb = qrow + mt*16;
                float sfac[4];
                #pragma unroll
                for (int r = 0; r < 4; ++r) {
                    if (masked) {
                        int i = rb + g*4 + r;
                        #pragma unroll
                        for (int sub = 0; sub < 4; ++sub) {
                            int j = j0 + sub*16 + l15;
                            if (j > i) sfr[mt][sub][r] = -3e38f;
                        }
                    }
                    float mx = fmaxf(fmaxf(sfr[mt][0][r], sfr[mt][1][r]),
                                     fmaxf(sfr[mt][2][r], sfr[mt][3][r]));
                    #pragma unroll
                    for (int m = 1; m < 16; m <<= 1) mx = fmaxf(mx, __shfl_xor(mx, m));
                    float mnew = fmaxf(mrow[mt][r], mx);
                    sfac[r] = __builtin_amdgcn_exp2f(mrow[mt][r] - mnew);
                    mrow[mt][r] = mnew;
                    float p0 = __builtin_amdgcn_exp2f(sfr[mt][0][r] - mnew);
                    float p1 = __builtin_amdgcn_exp2f(sfr[mt][1][r] - mnew);
                    float p2 = __builtin_amdgcn_exp2f(sfr[mt][2][r] - mnew);
                    float p3 = __builtin_amdgcn_exp2f(sfr[mt][3][r] - mnew);
                    sfr[mt][0][r] = p0; sfr[mt][1][r] = p1;
                    sfr[mt][2][r] = p2; sfr[mt][3][r] = p3;
                    float ps = (p0 + p1) + (p2 + p3);
                    #pragma unroll
                    for (int m = 1; m < 16; m <<= 1) ps += __shfl_xor(ps, m);
                    lrow[mt][r] = lrow[mt][r] * sfac[r] + ps;
                }
                #pragma unroll
                for (int sub = 0; sub < 4; ++sub)
                    #pragma unroll
                    for (int r = 0; r < 4; ++r)
                        Pl[w][(g*4 + r) * LPS + sub*16 + l15] = (bf16)sfr[mt][sub][r];
                #pragma unroll
                for (int dt = 0; dt < 8; ++dt)
                    #pragma unroll
                    for (int r = 0; r < 4; ++r) o[mt][dt][r] *= sfac[r];
                pf[mt][0] = *reinterpret_cast<const bf16x8*>(&Pl[w][l15 * LPS + g * 8]);
                pf[mt][1] = *reinterpret_cast<const bf16x8*>(&Pl[w][l15 * LPS + 32 + g * 8]);
            }

            // ---- PV: O[32q][128d] += P[32q][64j] V[64j][128d]
            #pragma unroll
            for (int dt = 0; dt < 8; ++dt) {
                int vrow = dt*16 + l15;
                bf16x8 va = *reinterpret_cast<const bf16x8*>(
                    &Vl[cur][vrow*64 + ((g ^ sw) * 8)]);
                bf16x8 vb = *reinterpret_cast<const bf16x8*>(
                    &Vl[cur][vrow*64 + (((4 + g) ^ sw) * 8)]);
                o[0][dt] = __builtin_amdgcn_mfma_f32_16x16x32_bf16(pf[0][0], va, o[0][dt], 0, 0, 0);
                o[0][dt] = __builtin_amdgcn_mfma_f32_16x16x32_bf16(pf[0][1], vb, o[0][dt], 0, 0, 0);
                o[1][dt] = __builtin_amdgcn_mfma_f32_16x16x32_bf16(pf[1][0], va, o[1][dt], 0, 0, 0);
                o[1][dt] = __builtin_amdgcn_mfma_f32_16x16x32_bf16(pf[1][1], vb, o[1][dt], 0, 0, 0);
            }
        }
    }

    #pragma unroll
    for (int mt = 0; mt < 2; ++mt)
        #pragma unroll
        for (int r = 0; r < 4; ++r) {
            float inv = 1.0f / lrow[mt][r];
            int i = qrow + mt*16 + g*4 + r;
            #pragma unroll
            for (int dt = 0; dt < 8; ++dt)
                attn[(size_t)i * 2048 + h * 128 + dt*16 + l15] = (bf16)(o[mt][dt][r] * inv);
        }
}

// ---------------------------------------------------------------- launch
extern "C" void kernel_launch(void* const* d_in, const int* in_sizes, int n_in,
                              void* d_out, int out_size, void* d_ws, size_t ws_size,
                              hipStream_t stream) {
    const float* x    = (const float*)d_in[0];
    const float* cosb = (const float*)d_in[1];
    const float* sinb = (const float*)d_in[2];
    // d_in[3] = mask (unused: causal, start_pos=0)
    const float* wq   = (const float*)d_in[4];
    const float* wkva = (const float*)d_in[5];
    const float* kvw  = (const float*)d_in[6];
    const float* wkvb = (const float*)d_in[7];
    const float* wo   = (const float*)d_in[8];
    // d_in[9] = start_pos (0)

    char* ws = (char*)d_ws;
    bf16* x_bf    = (bf16*)(ws + 0);          // 16.7MB; later reused as kvnorm, then attn
    bf16* kvnorm  = (bf16*)(ws + 0);
    bf16* attn    = (bf16*)(ws + 0);
    bf16* wq_bf   = (bf16*)(ws + 16777216);
    bf16* wkva_bf = (bf16*)(ws + 25165824);
    bf16* wkvb_bf = (bf16*)(ws + 29622272);
    bf16* wo_bf   = (bf16*)(ws + 35913728);
    bf16* q_bf    = (bf16*)(ws + 44302336);
    bf16* kvfull  = (bf16*)(ws + 61079552);
    bf16* kpe     = (bf16*)(ws + 69992448);
    bf16* kvb     = (bf16*)(ws + 70516736);
    bf16* vt      = (bf16*)(ws + 95682560);
    // total: 112459776 bytes

    f32_to_bf16_kernel<<<dim3(512), dim3(256), 0, stream>>>(x,    x_bf,    4096*2048);
    f32_to_bf16_kernel<<<dim3(512), dim3(256), 0, stream>>>(wq,   wq_bf,   2048*2048);
    f32_to_bf16_kernel<<<dim3(512), dim3(256), 0, stream>>>(wkva, wkva_bf, 1088*2048);
    f32_to_bf16_kernel<<<dim3(512), dim3(256), 0, stream>>>(wkvb, wkvb_bf, 3072*1024);
    f32_to_bf16_kernel<<<dim3(512), dim3(256), 0, stream>>>(wo,   wo_bf,   2048*2048);

    gemm_bt_kernel<true><<<dim3(16, 32), dim3(256), 0, stream>>>(x_bf, wq_bf,   q_bf,   4096, 2048, 2048);
    gemm_bt_kernel<true><<<dim3(9,  32), dim3(256), 0, stream>>>(x_bf, wkva_bf, kvfull, 4096, 1088, 2048);

    prep_q_kernel <<<dim3(4096), dim3(256), 0, stream>>>(q_bf, cosb, sinb);
    prep_kv_kernel<<<dim3(4096), dim3(256), 0, stream>>>(kvfull, kvw, cosb, sinb, kvnorm, kpe);

    gemm_bt_kernel<true><<<dim3(24, 32), dim3(256), 0, stream>>>(kvnorm, wkvb_bf, kvb, 4096, 3072, 1024);

    build_vt_kernel<<<dim3(64, 16), dim3(256), 0, stream>>>(kvb, vt);

    attn_kernel<<<dim3(32, 16), dim3(256), 0, stream>>>(q_bf, kvb, kpe, vt, attn);

    gemm_bt_kernel<false><<<dim3(16, 32), dim3(256), 0, stream>>>(attn, wo_bf, (float*)d_out, 4096, 2048, 2048);
}